// Round 1
// baseline (483.949 us; speedup 1.0000x reference)
//
#include <hip/hip_runtime.h>

#define NGRAPH 512
#define DF 96
#define DHID 10
#define HALF 48            // feature split: 2 halves of 48 so LDS partials fit
#define EDGE_BLOCKS 128    // per half; 256 blocks total = 1 per CU
#define EDGE_THREADS 1024

// ---------------------------------------------------------------------------
// Kernel 1: fused edge-scatter + graph-pool partial sums.
// sums[g][f] += edge_attr[e] * x[src[e]][f]  for g = batch[dst[e]]
// Per block: LDS partial accumulator over all 512 graphs x 48 features,
// then one atomic flush to global sums.
// ---------------------------------------------------------------------------
__global__ __launch_bounds__(EDGE_THREADS) void edge_aggregate_kernel(
    const int* __restrict__ edge_index,   // [2*E] (src row, then dst row)
    const float* __restrict__ edge_attr,  // [E]
    const int* __restrict__ batch,        // [N] sorted graph id per node
    const float* __restrict__ x,          // [N*DF]
    float* __restrict__ sums,             // [NGRAPH*DF] global accumulator
    int E)
{
    __shared__ float part[NGRAPH * HALF];             // 98304 B
    const int half  = blockIdx.y;                     // which 48-feature half
    const int fbase = half * HALF;

    for (int i = threadIdx.x; i < NGRAPH * HALF; i += EDGE_THREADS)
        part[i] = 0.f;
    __syncthreads();

    const int lane = threadIdx.x & 63;
    const int wid  = blockIdx.x * (EDGE_THREADS >> 6) + (threadIdx.x >> 6);
    const int nw   = gridDim.x * (EDGE_THREADS >> 6);
    const int* __restrict__ srcA = edge_index;
    const int* __restrict__ dstA = edge_index + E;

    // one wave per edge iteration: lanes 0..47 cover the 48 features.
    // LDS addresses part[g*48 + lane]: lanes 0-31 hit 32 distinct banks,
    // lanes 32-47 are 2-way (free).
    for (int e = wid; e < E; e += nw) {
        const int   s = srcA[e];        // wave-uniform broadcast loads
        const int   d = dstA[e];
        const float w = edge_attr[e];
        const int   g = batch[d];
        if (lane < HALF) {
            const float xv = x[(size_t)s * DF + fbase + lane];
            atomicAdd(&part[g * HALF + lane], w * xv);
        }
    }
    __syncthreads();

    // flush block partials to global (few atomics: 24576 per block)
    for (int i = threadIdx.x; i < NGRAPH * HALF; i += EDGE_THREADS) {
        const float v = part[i];
        if (v != 0.f) {
            const int g = i / HALF;
            const int f = i - g * HALF;
            atomicAdd(&sums[g * DF + fbase + f], v);
        }
    }
}

// ---------------------------------------------------------------------------
// Kernel 2: mean-pool (counts via binary search on sorted batch) + MLP head.
// One thread per graph; 512 threads in one block.
// ---------------------------------------------------------------------------
__global__ __launch_bounds__(NGRAPH) void finish_kernel(
    const float* __restrict__ sums,   // [NGRAPH*DF]
    const int* __restrict__ batch,    // [N] sorted
    int nNodes,
    const float* __restrict__ W1,     // [DF*DHID]
    const float* __restrict__ b1,     // [DHID]
    const float* __restrict__ W2,     // [DHID]
    const float* __restrict__ b2,     // [1]
    float* __restrict__ out)          // [NGRAPH]
{
    __shared__ float sW1[DF * DHID];
    __shared__ float sb1[DHID];
    __shared__ float sW2[DHID];
    const int t = threadIdx.x;
    for (int i = t; i < DF * DHID; i += blockDim.x) sW1[i] = W1[i];
    if (t < DHID) { sb1[t] = b1[t]; sW2[t] = W2[t]; }
    __syncthreads();

    const int g = t;

    // counts[g] = upper_bound(batch, g) - lower_bound(batch, g)
    int lo = 0, hi = nNodes;
    while (lo < hi) { int m = (lo + hi) >> 1; if (batch[m] < g) lo = m + 1; else hi = m; }
    const int lb = lo;
    hi = nNodes;
    while (lo < hi) { int m = (lo + hi) >> 1; if (batch[m] <= g) lo = m + 1; else hi = m; }
    const int cnt = lo - lb;
    const float inv = 1.f / fmaxf((float)cnt, 1.f);

    float hid[DHID];
#pragma unroll
    for (int j = 0; j < DHID; ++j) hid[j] = sb1[j];

    for (int f = 0; f < DF; ++f) {
        const float z = fmaxf(sums[g * DF + f] * inv, 0.f);   // relu(pooled)
#pragma unroll
        for (int j = 0; j < DHID; ++j) hid[j] += z * sW1[f * DHID + j];
    }

    float o = b2[0];
#pragma unroll
    for (int j = 0; j < DHID; ++j) o += fmaxf(hid[j], 0.f) * sW2[j];
    out[g] = o;
}

// ---------------------------------------------------------------------------
extern "C" void kernel_launch(void* const* d_in, const int* in_sizes, int n_in,
                              void* d_out, int out_size, void* d_ws, size_t ws_size,
                              hipStream_t stream) {
    const float* x          = (const float*)d_in[0];
    const int*   edge_index = (const int*)  d_in[1];
    const float* edge_attr  = (const float*)d_in[2];
    const int*   batch      = (const int*)  d_in[3];
    const float* W1         = (const float*)d_in[4];
    const float* b1         = (const float*)d_in[5];
    const float* W2         = (const float*)d_in[6];
    const float* b2         = (const float*)d_in[7];

    const int E = in_sizes[1] / 2;   // 800000
    const int N = in_sizes[3];       // 50000

    float* sums = (float*)d_ws;      // [NGRAPH*DF] = 196608 B
    hipMemsetAsync(sums, 0, NGRAPH * DF * sizeof(float), stream);

    dim3 grid(EDGE_BLOCKS, 2);
    edge_aggregate_kernel<<<grid, EDGE_THREADS, 0, stream>>>(
        edge_index, edge_attr, batch, x, sums, E);

    finish_kernel<<<1, NGRAPH, 0, stream>>>(
        sums, batch, N, W1, b1, W2, b2, (float*)d_out);
}

// Round 2
// 336.363 us; speedup vs baseline: 1.4388x; 1.4388x over previous
//
#include <hip/hip_runtime.h>

#define NGRAPH 512
#define DF 96
#define DHID 10

// ---------------------------------------------------------------------------
// Kernel A: per-edge graph id + histogram (LDS-privatized).
// ---------------------------------------------------------------------------
__global__ __launch_bounds__(256) void hist_kernel(
    const int* __restrict__ edge_index,      // [2*E]
    const int* __restrict__ batch,           // [N]
    int E,
    int* __restrict__ hist,                  // [NGRAPH] (pre-zeroed)
    unsigned short* __restrict__ g16)        // [E] cached graph id per edge
{
    __shared__ int lh[NGRAPH];
    for (int i = threadIdx.x; i < NGRAPH; i += 256) lh[i] = 0;
    __syncthreads();
    const int* __restrict__ dst = edge_index + E;
    const int stride = gridDim.x * 256;
    for (int e = blockIdx.x * 256 + threadIdx.x; e < E; e += stride) {
        const int g = batch[dst[e]];
        g16[e] = (unsigned short)g;
        atomicAdd(&lh[g], 1);
    }
    __syncthreads();
    for (int i = threadIdx.x; i < NGRAPH; i += 256)
        if (lh[i]) atomicAdd(&hist[i], lh[i]);
}

// ---------------------------------------------------------------------------
// Kernel B: exclusive scan of the 512-bin histogram (one block).
// ---------------------------------------------------------------------------
__global__ __launch_bounds__(NGRAPH) void scan_kernel(
    const int* __restrict__ hist,
    int* __restrict__ off,        // [NGRAPH+1]
    int* __restrict__ cursor,     // [NGRAPH]
    int E)
{
    __shared__ int sh[NGRAPH];
    const int t = threadIdx.x;
    const int v = hist[t];
    sh[t] = v;
    __syncthreads();
    for (int d = 1; d < NGRAPH; d <<= 1) {
        const int add = (t >= d) ? sh[t - d] : 0;
        __syncthreads();
        sh[t] += add;
        __syncthreads();
    }
    const int excl = sh[t] - v;
    off[t] = excl;
    cursor[t] = excl;
    if (t == NGRAPH - 1) off[NGRAPH] = E;
}

// ---------------------------------------------------------------------------
// Kernel C: counting-sort scatter of (src, w) into graph-contiguous order.
// ---------------------------------------------------------------------------
__global__ __launch_bounds__(256) void scatter_kernel(
    const int* __restrict__ edge_index,
    const float* __restrict__ edge_attr,
    const unsigned short* __restrict__ g16,
    int E,
    int* __restrict__ cursor,
    int* __restrict__ es,
    float* __restrict__ ew)
{
    const int stride = gridDim.x * 256;
    for (int e = blockIdx.x * 256 + threadIdx.x; e < E; e += stride) {
        const int g = g16[e];
        const int p = atomicAdd(&cursor[g], 1);
        es[p] = edge_index[e];       // src
        ew[p] = edge_attr[e];
    }
}

// ---------------------------------------------------------------------------
// Kernel D: per-graph gather + register-accumulate.
// Block = 1 graph, 4 waves. Wave layout: 8 edge-groups x 8 feature-lanes.
// Each 8-lane group reads one x row as 8 consecutive float4 (coalesced),
// 3 passes cover the 96 features. Accumulate in 12 regs/lane, shfl-reduce
// across edge-groups, LDS-reduce across waves.
// ---------------------------------------------------------------------------
__global__ __launch_bounds__(256) void aggregate_kernel(
    const int* __restrict__ es,
    const float* __restrict__ ew,
    const int* __restrict__ off,
    const float* __restrict__ x,     // [N*DF]
    float* __restrict__ sums)        // [NGRAPH*DF]
{
    const int g     = blockIdx.x;
    const int start = off[g];
    const int end   = off[g + 1];
    const int wave  = threadIdx.x >> 6;
    const int lane  = threadIdx.x & 63;
    const int eg    = lane >> 3;          // edge slot in 8-edge slab
    const int fc    = lane & 7;           // float4 chunk lane

    float acc[12];
#pragma unroll
    for (int i = 0; i < 12; ++i) acc[i] = 0.f;

    // software-pipelined edge loop: e advances by 32 per wave iteration
    int e = start + wave * 8 + eg;
    int   s = (e < end) ? es[e] : 0;
    float w = (e < end) ? ew[e] : 0.f;
    while (e < end) {
        const int en = e + 32;
        const int   sn = (en < end) ? es[en] : 0;
        const float wn = (en < end) ? ew[en] : 0.f;

        const float4* __restrict__ row = (const float4*)x + (size_t)s * 24;
#pragma unroll
        for (int c = 0; c < 3; ++c) {
            const float4 v = row[fc + c * 8];
            acc[c * 4 + 0] += w * v.x;
            acc[c * 4 + 1] += w * v.y;
            acc[c * 4 + 2] += w * v.z;
            acc[c * 4 + 3] += w * v.w;
        }
        e = en; s = sn; w = wn;
    }

    // reduce across the 8 edge-groups (lane bits 3..5)
#pragma unroll
    for (int m = 8; m <= 32; m <<= 1) {
#pragma unroll
        for (int i = 0; i < 12; ++i) acc[i] += __shfl_xor(acc[i], m, 64);
    }

    __shared__ float sh[4][DF];
    if (eg == 0) {
#pragma unroll
        for (int c = 0; c < 3; ++c)
#pragma unroll
            for (int k = 0; k < 4; ++k)
                sh[wave][c * 32 + fc * 4 + k] = acc[c * 4 + k];
    }
    __syncthreads();
    if (threadIdx.x < DF) {
        sums[g * DF + threadIdx.x] = sh[0][threadIdx.x] + sh[1][threadIdx.x]
                                   + sh[2][threadIdx.x] + sh[3][threadIdx.x];
    }
}

// ---------------------------------------------------------------------------
// Kernel E: mean-pool (counts via binary search on sorted batch) + MLP head.
// ---------------------------------------------------------------------------
__global__ __launch_bounds__(NGRAPH) void finish_kernel(
    const float* __restrict__ sums,
    const int* __restrict__ batch,
    int nNodes,
    const float* __restrict__ W1,
    const float* __restrict__ b1,
    const float* __restrict__ W2,
    const float* __restrict__ b2,
    float* __restrict__ out)
{
    __shared__ float sW1[DF * DHID];
    __shared__ float sb1[DHID];
    __shared__ float sW2[DHID];
    const int t = threadIdx.x;
    for (int i = t; i < DF * DHID; i += blockDim.x) sW1[i] = W1[i];
    if (t < DHID) { sb1[t] = b1[t]; sW2[t] = W2[t]; }
    __syncthreads();

    const int g = t;
    int lo = 0, hi = nNodes;
    while (lo < hi) { int m = (lo + hi) >> 1; if (batch[m] < g) lo = m + 1; else hi = m; }
    const int lb = lo;
    hi = nNodes;
    while (lo < hi) { int m = (lo + hi) >> 1; if (batch[m] <= g) lo = m + 1; else hi = m; }
    const int cnt = lo - lb;
    const float inv = 1.f / fmaxf((float)cnt, 1.f);

    float hid[DHID];
#pragma unroll
    for (int j = 0; j < DHID; ++j) hid[j] = sb1[j];

    for (int f = 0; f < DF; ++f) {
        const float z = fmaxf(sums[g * DF + f] * inv, 0.f);
#pragma unroll
        for (int j = 0; j < DHID; ++j) hid[j] += z * sW1[f * DHID + j];
    }

    float o = b2[0];
#pragma unroll
    for (int j = 0; j < DHID; ++j) o += fmaxf(hid[j], 0.f) * sW2[j];
    out[g] = o;
}

// ---------------------------------------------------------------------------
extern "C" void kernel_launch(void* const* d_in, const int* in_sizes, int n_in,
                              void* d_out, int out_size, void* d_ws, size_t ws_size,
                              hipStream_t stream) {
    const float* x          = (const float*)d_in[0];
    const int*   edge_index = (const int*)  d_in[1];
    const float* edge_attr  = (const float*)d_in[2];
    const int*   batch      = (const int*)  d_in[3];
    const float* W1         = (const float*)d_in[4];
    const float* b1         = (const float*)d_in[5];
    const float* W2         = (const float*)d_in[6];
    const float* b2         = (const float*)d_in[7];

    const int E = in_sizes[1] / 2;   // 800000
    const int N = in_sizes[3];       // 50000

    // workspace layout (bytes)
    char* ws = (char*)d_ws;
    int*            es     = (int*)            ws;                       // E ints
    float*          ew     = (float*)         (ws + (size_t)4 * E);      // E floats
    unsigned short* g16    = (unsigned short*)(ws + (size_t)8 * E);      // E u16
    char* tail = ws + (size_t)10 * E;
    // align to 256
    tail = (char*)(((size_t)tail + 255) & ~(size_t)255);
    int*   hist   = (int*)tail;                  // NGRAPH
    int*   off    = hist + NGRAPH;               // NGRAPH+1
    int*   cursor = off + NGRAPH + 1;            // NGRAPH
    float* sums   = (float*)(cursor + NGRAPH);   // NGRAPH*DF

    hipMemsetAsync(hist, 0, NGRAPH * sizeof(int), stream);

    hist_kernel<<<256, 256, 0, stream>>>(edge_index, batch, E, hist, g16);
    scan_kernel<<<1, NGRAPH, 0, stream>>>(hist, off, cursor, E);
    scatter_kernel<<<512, 256, 0, stream>>>(edge_index, edge_attr, g16, E,
                                            cursor, es, ew);
    aggregate_kernel<<<NGRAPH, 256, 0, stream>>>(es, ew, off, x, sums);
    finish_kernel<<<1, NGRAPH, 0, stream>>>(sums, batch, N, W1, b1, W2, b2,
                                            (float*)d_out);
}

// Round 3
// 100.254 us; speedup vs baseline: 4.8272x; 3.3551x over previous
//
#include <hip/hip_runtime.h>

#define NGRAPH 512
#define DF 96
#define DHID 10
#define NCHUNK 256
#define HTHREADS 1024

// ---------------------------------------------------------------------------
// Kernel A: per-chunk histogram over graph ids + cache g per edge.
// Block c owns edges [c*chunk, (c+1)*chunk). hist2d[c][g] = count.
// ---------------------------------------------------------------------------
__global__ __launch_bounds__(HTHREADS) void hist_kernel(
    const int* __restrict__ edge_index,      // [2*E]
    const int* __restrict__ batch,           // [N]
    int E, int chunk,
    int* __restrict__ hist2d,                // [NCHUNK*NGRAPH]
    unsigned short* __restrict__ g16)        // [E]
{
    __shared__ int lh[NGRAPH];
    for (int i = threadIdx.x; i < NGRAPH; i += HTHREADS) lh[i] = 0;
    __syncthreads();

    const int* __restrict__ dst = edge_index + E;
    const int lo = blockIdx.x * chunk;
    const int hi = min(E, lo + chunk);
    for (int e = lo + threadIdx.x; e < hi; e += HTHREADS) {
        const int g = batch[dst[e]];
        g16[e] = (unsigned short)g;
        atomicAdd(&lh[g], 1);
    }
    __syncthreads();
    for (int i = threadIdx.x; i < NGRAPH; i += HTHREADS)
        hist2d[blockIdx.x * NGRAPH + i] = lh[i];
}

// ---------------------------------------------------------------------------
// Kernel B: column-sum + exclusive scan + per-chunk base offsets.
// One block, 512 threads; thread g owns graph g.
// ---------------------------------------------------------------------------
__global__ __launch_bounds__(NGRAPH) void scan_kernel(
    const int* __restrict__ hist2d,   // [NCHUNK*NGRAPH]
    int* __restrict__ base2d,         // [NCHUNK*NGRAPH]
    int* __restrict__ off,            // [NGRAPH+1]
    int E)
{
    __shared__ int sh[NGRAPH];
    const int g = threadIdx.x;

    int total = 0;
    for (int c = 0; c < NCHUNK; ++c) total += hist2d[c * NGRAPH + g];
    sh[g] = total;
    __syncthreads();
    for (int d = 1; d < NGRAPH; d <<= 1) {
        const int add = (g >= d) ? sh[g - d] : 0;
        __syncthreads();
        sh[g] += add;
        __syncthreads();
    }
    const int excl = sh[g] - total;
    off[g] = excl;
    if (g == NGRAPH - 1) off[NGRAPH] = E;

    int run = excl;
    for (int c = 0; c < NCHUNK; ++c) {
        base2d[c * NGRAPH + g] = run;
        run += hist2d[c * NGRAPH + g];
    }
}

// ---------------------------------------------------------------------------
// Kernel C: scatter into graph-contiguous order. LDS cursors only —
// zero global atomics. Packed int2 {src, bits(w)} stores.
// ---------------------------------------------------------------------------
__global__ __launch_bounds__(HTHREADS) void scatter_kernel(
    const int* __restrict__ edge_index,
    const float* __restrict__ edge_attr,
    const unsigned short* __restrict__ g16,
    const int* __restrict__ base2d,
    int E, int chunk,
    int2* __restrict__ ed)            // [E] packed (src, w)
{
    __shared__ int lcur[NGRAPH];
    for (int i = threadIdx.x; i < NGRAPH; i += HTHREADS)
        lcur[i] = base2d[blockIdx.x * NGRAPH + i];
    __syncthreads();

    const int lo = blockIdx.x * chunk;
    const int hi = min(E, lo + chunk);
    for (int e = lo + threadIdx.x; e < hi; e += HTHREADS) {
        const int g = g16[e];
        const int p = atomicAdd(&lcur[g], 1);
        ed[p] = make_int2(edge_index[e], __float_as_int(edge_attr[e]));
    }
}

// ---------------------------------------------------------------------------
// Kernel D: per-graph gather + register-accumulate.
// Block = 1 graph, 4 waves; 8 edge-groups x 8 feature-lanes per wave.
// ---------------------------------------------------------------------------
__global__ __launch_bounds__(256) void aggregate_kernel(
    const int2* __restrict__ ed,
    const int* __restrict__ off,
    const float* __restrict__ x,     // [N*DF]
    float* __restrict__ sums)        // [NGRAPH*DF]
{
    const int g     = blockIdx.x;
    const int start = off[g];
    const int end   = off[g + 1];
    const int wave  = threadIdx.x >> 6;
    const int lane  = threadIdx.x & 63;
    const int eg    = lane >> 3;
    const int fc    = lane & 7;

    float acc[12];
#pragma unroll
    for (int i = 0; i < 12; ++i) acc[i] = 0.f;

    int e = start + wave * 8 + eg;
    int2 sw = (e < end) ? ed[e] : make_int2(0, 0);
    while (e < end) {
        const int en = e + 32;
        const int2 swn = (en < end) ? ed[en] : make_int2(0, 0);

        const float w = __int_as_float(sw.y);
        const float4* __restrict__ row = (const float4*)x + (size_t)sw.x * 24;
#pragma unroll
        for (int c = 0; c < 3; ++c) {
            const float4 v = row[fc + c * 8];
            acc[c * 4 + 0] += w * v.x;
            acc[c * 4 + 1] += w * v.y;
            acc[c * 4 + 2] += w * v.z;
            acc[c * 4 + 3] += w * v.w;
        }
        e = en; sw = swn;
    }

#pragma unroll
    for (int m = 8; m <= 32; m <<= 1) {
#pragma unroll
        for (int i = 0; i < 12; ++i) acc[i] += __shfl_xor(acc[i], m, 64);
    }

    __shared__ float sh[4][DF];
    if (eg == 0) {
#pragma unroll
        for (int c = 0; c < 3; ++c)
#pragma unroll
            for (int k = 0; k < 4; ++k)
                sh[wave][c * 32 + fc * 4 + k] = acc[c * 4 + k];
    }
    __syncthreads();
    if (threadIdx.x < DF) {
        sums[g * DF + threadIdx.x] = sh[0][threadIdx.x] + sh[1][threadIdx.x]
                                   + sh[2][threadIdx.x] + sh[3][threadIdx.x];
    }
}

// ---------------------------------------------------------------------------
// Kernel E: mean-pool (counts via binary search on sorted batch) + MLP head.
// ---------------------------------------------------------------------------
__global__ __launch_bounds__(NGRAPH) void finish_kernel(
    const float* __restrict__ sums,
    const int* __restrict__ batch,
    int nNodes,
    const float* __restrict__ W1,
    const float* __restrict__ b1,
    const float* __restrict__ W2,
    const float* __restrict__ b2,
    float* __restrict__ out)
{
    __shared__ float sW1[DF * DHID];
    __shared__ float sb1[DHID];
    __shared__ float sW2[DHID];
    const int t = threadIdx.x;
    for (int i = t; i < DF * DHID; i += blockDim.x) sW1[i] = W1[i];
    if (t < DHID) { sb1[t] = b1[t]; sW2[t] = W2[t]; }
    __syncthreads();

    const int g = t;
    int lo = 0, hi = nNodes;
    while (lo < hi) { int m = (lo + hi) >> 1; if (batch[m] < g) lo = m + 1; else hi = m; }
    const int lb = lo;
    hi = nNodes;
    while (lo < hi) { int m = (lo + hi) >> 1; if (batch[m] <= g) lo = m + 1; else hi = m; }
    const int cnt = lo - lb;
    const float inv = 1.f / fmaxf((float)cnt, 1.f);

    float hid[DHID];
#pragma unroll
    for (int j = 0; j < DHID; ++j) hid[j] = sb1[j];

    for (int f = 0; f < DF; ++f) {
        const float z = fmaxf(sums[g * DF + f] * inv, 0.f);
#pragma unroll
        for (int j = 0; j < DHID; ++j) hid[j] += z * sW1[f * DHID + j];
    }

    float o = b2[0];
#pragma unroll
    for (int j = 0; j < DHID; ++j) o += fmaxf(hid[j], 0.f) * sW2[j];
    out[g] = o;
}

// ---------------------------------------------------------------------------
extern "C" void kernel_launch(void* const* d_in, const int* in_sizes, int n_in,
                              void* d_out, int out_size, void* d_ws, size_t ws_size,
                              hipStream_t stream) {
    const float* x          = (const float*)d_in[0];
    const int*   edge_index = (const int*)  d_in[1];
    const float* edge_attr  = (const float*)d_in[2];
    const int*   batch      = (const int*)  d_in[3];
    const float* W1         = (const float*)d_in[4];
    const float* b1         = (const float*)d_in[5];
    const float* W2         = (const float*)d_in[6];
    const float* b2         = (const float*)d_in[7];

    const int E = in_sizes[1] / 2;   // 800000
    const int N = in_sizes[3];       // 50000
    const int chunk = (E + NCHUNK - 1) / NCHUNK;

    // workspace layout
    char* ws = (char*)d_ws;
    int2*           ed   = (int2*)ws;                                // 8*E bytes
    unsigned short* g16  = (unsigned short*)(ws + (size_t)8 * E);    // 2*E
    char* tail = ws + (size_t)10 * E;
    tail = (char*)(((size_t)tail + 255) & ~(size_t)255);
    int*   hist2d = (int*)tail;                       // NCHUNK*NGRAPH
    int*   base2d = hist2d + NCHUNK * NGRAPH;         // NCHUNK*NGRAPH
    int*   off    = base2d + NCHUNK * NGRAPH;         // NGRAPH+1
    float* sums   = (float*)(off + NGRAPH + 2);       // NGRAPH*DF

    hist_kernel<<<NCHUNK, HTHREADS, 0, stream>>>(edge_index, batch, E, chunk,
                                                 hist2d, g16);
    scan_kernel<<<1, NGRAPH, 0, stream>>>(hist2d, base2d, off, E);
    scatter_kernel<<<NCHUNK, HTHREADS, 0, stream>>>(edge_index, edge_attr, g16,
                                                    base2d, E, chunk, ed);
    aggregate_kernel<<<NGRAPH, 256, 0, stream>>>(ed, off, x, sums);
    finish_kernel<<<1, NGRAPH, 0, stream>>>(sums, batch, N, W1, b1, W2, b2,
                                            (float*)d_out);
}